// Round 3
// baseline (127.697 us; speedup 1.0000x reference)
//
#include <hip/hip_runtime.h>
#include <float.h>
#include <math.h>

#define BATCH 4
#define NPTS 4096
#define BLK 256
#define QCH 8                      // queries/thread, chamfer
#define QR 4                       // queries/thread, repulsion
#define SEG_CH 64                  // chamfer segments (64 pts each)
#define TPTS_CH 64
#define SEG_R 32                   // repulsion segments (128 pts each)
#define TPTS_R 128
#define H2 (0.03f * 0.03f)
#define RADIUS_C 0.07f
#define EPS_C 1e-12f
#define T2 0.05f                   // rep d^2 cutoff: excluded contribs ~1e-25
#define NQ (BATCH * NPTS)          // 16384
#define NCH (2 * NQ)               // 32768 chamfer (type,b,q) rows

// d_ws (16 MB):
//   hdr    : float accum[2] + uint cnt + pad (16 B)  @ 0  (zeroed by partial blk 0)
//   minseg : float [SEG_CH][NCH]   (8 MB)            @ 16
//   top4   : float4[SEG_R][NQ]     (8 MB)            @ 16 + 8 MB
//
// R10 theory: dur_us = poison fill (~42us fixed) + partial + merge. R8 algebra
// gives merge ~27us at 192 blocks (0.75/CU, latency-exposed). Fix merge: 1024
// blocks, seg-split across thread groups + LDS tree -> ~1 latency round, ~BW
// floor (16MB -> ~4us). Partial: 1536 uniform-duration blocks (6/CU, no tail):
// chamfer QCH=8 x 64t (1024 blks), rep QR=4 x 128t (512 blks) - equal pair
// count per block. Natural VGPR (~52) already gives 8 waves/SIMD; no forced
// launch_bounds min-waves (spill risk).

template <bool EXCL>
__device__ __forceinline__ void rep_loop(
    const float4* __restrict__ s, int base, const int (&q)[QR],
    const float (&nx)[QR], const float (&ny)[QR], const float (&nz)[QR],
    float (&m)[QR][4])
{
    #pragma unroll 2
    for (int j = 0; j < TPTS_R; ++j) {
        float4 t = s[j];
        #pragma unroll
        for (int r = 0; r < QR; ++r) {
            float hv = fmaf(nx[r], t.x, fmaf(ny[r], t.y, fmaf(nz[r], t.z, t.w)));
            if (EXCL) hv = (base + j == q[r]) ? FLT_MAX : hv;   // exclude self
            if (__any(hv < m[r][3])) {                          // per-query gate, rare
                float n0 = fminf(m[r][0], hv); float u0 = fmaxf(m[r][0], hv);
                float n1 = fminf(m[r][1], u0); float u1 = fmaxf(m[r][1], u0);
                float n2 = fminf(m[r][2], u1); float u2 = fmaxf(m[r][2], u1);
                float n3 = fminf(m[r][3], u2);
                m[r][0] = n0; m[r][1] = n1; m[r][2] = n2; m[r][3] = n3;
            }
        }
    }
}

// 1536 blocks, pattern [C,C,R]: chamfer cid = (g/3)*2 + g%3 in [0,1024),
// rep rid = g/3 in [0,512). Every block = 131072 pair-evals (no tail).
__global__ __launch_bounds__(BLK) void partial_kernel(
    const float* __restrict__ pred, const float* __restrict__ gt,
    float* __restrict__ minseg, float4* __restrict__ top4,
    unsigned int* __restrict__ hdr)
{
    __shared__ float4 s[TPTS_R];   // up to 128 x (x,y,z,|t|^2) = 2 KB

    if (blockIdx.x == 0 && threadIdx.x < 4)
        hdr[threadIdx.x] = 0u;     // zero accum[2]+cnt for merge

    const int g   = blockIdx.x;
    const int r3  = g % 3;
    const int id  = g / 3;
    const bool isrep = (r3 == 2);

    int type, b, qblk, seg;
    if (!isrep) {
        int cid = id * 2 + r3;     // [0,1024)
        qblk = cid & 1; type = (cid >> 1) & 1; b = (cid >> 2) & 3; seg = cid >> 4; // <64
    } else {
        qblk = id & 3; type = 2;   b = (id >> 2) & 3; seg = id >> 4;               // <32
    }
    const float* qbase = (type == 1) ? gt : pred;
    const float* tbase = (type == 0) ? gt : pred;
    const int npts = isrep ? TPTS_R : TPTS_CH;

    // stage npts targets: threads 0..npts/2-1, 2 points each, |t|^2 on the fly
    if (threadIdx.x < (npts >> 1)) {
        const float2* g2 = (const float2*)(tbase + ((size_t)b * NPTS + seg * npts) * 3);
        float2 a = g2[3 * threadIdx.x + 0];
        float2 c = g2[3 * threadIdx.x + 1];
        float2 e = g2[3 * threadIdx.x + 2];
        float t20 = fmaf(a.x, a.x, fmaf(a.y, a.y, c.x * c.x));
        float t21 = fmaf(c.y, c.y, fmaf(e.x, e.x, e.y * e.y));
        s[2 * threadIdx.x + 0] = make_float4(a.x, a.y, c.x, t20);
        s[2 * threadIdx.x + 1] = make_float4(c.y, e.x, e.y, t21);
    }
    __syncthreads();

    if (!isrep) {
        const int q0 = qblk * (BLK * QCH) + threadIdx.x;      // qblk*2048 + tid
        float nx[QCH], ny[QCH], nz[QCH], q2[QCH], mn[QCH];
        #pragma unroll
        for (int k = 0; k < QCH; ++k) {
            const float* q = qbase + ((size_t)b * NPTS + q0 + k * BLK) * 3;
            float qx = q[0], qy = q[1], qz = q[2];
            q2[k] = fmaf(qx, qx, fmaf(qy, qy, qz * qz));
            nx[k] = -2.f * qx; ny[k] = -2.f * qy; nz[k] = -2.f * qz;
            mn[k] = FLT_MAX;
        }
        #pragma unroll 2
        for (int j = 0; j < TPTS_CH; j += 2) {
            float4 t0 = s[j], t1 = s[j + 1];
            #pragma unroll
            for (int k = 0; k < QCH; ++k) {
                float h0 = fmaf(nx[k], t0.x, fmaf(ny[k], t0.y, fmaf(nz[k], t0.z, t0.w)));
                float h1 = fmaf(nx[k], t1.x, fmaf(ny[k], t1.y, fmaf(nz[k], t1.z, t1.w)));
                mn[k] = fminf(fminf(mn[k], h0), h1);          // -> v_min3_f32
            }
        }
        float* row = minseg + (size_t)seg * NCH + (type * BATCH + b) * NPTS;
        #pragma unroll
        for (int k = 0; k < QCH; ++k)
            row[q0 + k * BLK] = mn[k] + q2[k];
    } else {
        const int qb = qblk * (BLK * QR) + threadIdx.x;       // qblk*1024 + tid
        int   q[QR];
        float nx[QR], ny[QR], nz[QR], q2[QR];
        float m[QR][4];
        #pragma unroll
        for (int r = 0; r < QR; ++r) {
            q[r] = qb + r * BLK;
            const float* qa = qbase + ((size_t)b * NPTS + q[r]) * 3;
            float qx = qa[0], qy = qa[1], qz = qa[2];
            q2[r] = fmaf(qx, qx, fmaf(qy, qy, qz * qz));
            nx[r] = -2.f * qx; ny[r] = -2.f * qy; nz[r] = -2.f * qz;
            // h-space cutoff init: h < T2 - q2  <=>  d2 < T2
            float a = T2 - q2[r];
            m[r][0] = a; m[r][1] = a; m[r][2] = a; m[r][3] = a;
        }
        const int base = seg * TPTS_R;
        // queries [qblk*1024, +1024) overlap targets [seg*128, +128) iff seg>>3==qblk
        if ((seg >> 3) == qblk)
            rep_loop<true >(s, base, q, nx, ny, nz, m);
        else
            rep_loop<false>(s, base, q, nx, ny, nz, m);

        float4* dst = top4 + (size_t)seg * NQ + b * NPTS;
        #pragma unroll
        for (int r = 0; r < QR; ++r)
            dst[q[r]] = make_float4(m[r][0] + q2[r], m[r][1] + q2[r],
                                    m[r][2] + q2[r], m[r][3] + q2[r]);
    }
}

// 1024 blocks: even = chamfer merge (512 x 64 queries), odd = rep merge
// (512 x 32 queries). Seg-range split across thread groups + LDS tree ->
// all loads of a thread independent (1 latency round). Last block finalizes.
__global__ __launch_bounds__(BLK) void merge_kernel(
    const float* __restrict__ minseg, const float4* __restrict__ top4,
    unsigned int* __restrict__ hdr, float* __restrict__ out)
{
    __shared__ float4 l4[8][32];                   // rep lists; aliased for chamfer
    __shared__ float warr[BLK / 64];
    float* red = (float*)l4;                       // [4][64] floats for chamfer

    float contrib = 0.f;
    int which;
    const int c = blockIdx.x >> 1;                 // [0,512)
    if (!(blockIdx.x & 1)) {
        // ---- chamfer: 64 queries, 4 groups x 16 segs ----
        const int q   = c * 64 + (threadIdx.x & 63);
        const int grp = threadIdx.x >> 6;          // 0..3
        float m = FLT_MAX;
        #pragma unroll                             // 16 independent loads in flight
        for (int u = 0; u < 16; ++u)
            m = fminf(m, minseg[(size_t)(grp * 16 + u) * NCH + q]);
        red[grp * 64 + (threadIdx.x & 63)] = m;
        __syncthreads();
        if (threadIdx.x < 64) {
            float mm = fminf(fminf(red[threadIdx.x],       red[64  + threadIdx.x]),
                             fminf(red[128 + threadIdx.x], red[192 + threadIdx.x]));
            contrib = fmaxf(mm, 0.f);              // clamp as in reference
        }
        which = 0;
    } else {
        // ---- repulsion: 32 queries, 8 groups x 4 segs ----
        const int q   = c * 32 + (threadIdx.x & 31);
        const int grp = threadIdx.x >> 5;          // 0..7
        float m0 = FLT_MAX, m1 = FLT_MAX, m2 = FLT_MAX, m3 = FLT_MAX;
        #pragma unroll                             // 4 float4 loads in flight
        for (int u = 0; u < 4; ++u) {
            float4 v = top4[(size_t)(grp * 4 + u) * NQ + q];
            const float vals[4] = {v.x, v.y, v.z, v.w};
            #pragma unroll
            for (int k = 0; k < 4; ++k) {
                float h = vals[k];
                if (h < m3) {                      // mostly T2 sentinel -> skip
                    float n0 = fminf(m0, h);  float u0 = fmaxf(m0, h);
                    float n1 = fminf(m1, u0); float u1 = fmaxf(m1, u0);
                    float n2 = fminf(m2, u1); float u2 = fmaxf(m2, u1);
                    float n3 = fminf(m3, u2);
                    m0 = n0; m1 = n1; m2 = n2; m3 = n3;
                }
            }
        }
        l4[grp][threadIdx.x & 31] = make_float4(m0, m1, m2, m3);
        __syncthreads();
        if (threadIdx.x < 32) {
            float p0 = FLT_MAX, p1 = FLT_MAX, p2 = FLT_MAX, p3 = FLT_MAX;
            #pragma unroll
            for (int g2 = 0; g2 < 8; ++g2) {
                float4 v = l4[g2][threadIdx.x];
                const float vals[4] = {v.x, v.y, v.z, v.w};
                #pragma unroll
                for (int k = 0; k < 4; ++k) {
                    float h = vals[k];
                    if (h < p3) {
                        float n0 = fminf(p0, h);  float u0 = fmaxf(p0, h);
                        float n1 = fminf(p1, u0); float u1 = fmaxf(p1, u0);
                        float n2 = fminf(p2, u1); float u2 = fmaxf(p2, u1);
                        float n3 = fminf(p3, u2);
                        p0 = n0; p1 = n1; p2 = n2; p3 = n3;
                    }
                }
            }
            const float ms[4] = {p0, p1, p2, p3};
            #pragma unroll
            for (int k = 0; k < 4; ++k) {
                float d2 = fmaxf(ms[k], EPS_C);
                float d  = sqrtf(d2);
                contrib += (RADIUS_C - d) * expf(-d2 * (1.f / H2));
            }
        }
        which = 1;
    }
    #pragma unroll
    for (int off = 32; off > 0; off >>= 1)
        contrib += __shfl_down(contrib, off, 64);
    if ((threadIdx.x & 63) == 0) warr[threadIdx.x >> 6] = contrib;
    __syncthreads();
    if (threadIdx.x == 0) {
        float bs = warr[0] + warr[1] + warr[2] + warr[3];
        float* accum = (float*)hdr;
        atomicAdd(&accum[which], bs);
        __threadfence();
        unsigned int old = atomicAdd(&hdr[2], 1u);
        if (old == 1023u) {                        // last block finalizes
            float a0 = atomicAdd(&accum[0], 0.f);  // coherent read
            float a1 = atomicAdd(&accum[1], 0.f);
            out[0] = 100.f * a0 * (1.f / NQ);
            out[1] = a1 * (1.f / (NQ * 4));
        }
    }
}

extern "C" void kernel_launch(void* const* d_in, const int* in_sizes, int n_in,
                              void* d_out, int out_size, void* d_ws, size_t ws_size,
                              hipStream_t stream)
{
    const float* pred = (const float*)d_in[0];
    const float* gt   = (const float*)d_in[1];

    unsigned int* hdr    = (unsigned int*)d_ws;
    float*        minseg = (float*)((char*)d_ws + 16);
    float4*       top4   = (float4*)((char*)d_ws + 16 + (size_t)SEG_CH * NCH * sizeof(float));

    partial_kernel<<<1536, BLK, 0, stream>>>(pred, gt, minseg, top4, hdr);
    merge_kernel<<<1024, BLK, 0, stream>>>(minseg, top4, hdr, (float*)d_out);
}

// Round 4
// 92.952 us; speedup vs baseline: 1.3738x; 1.3738x over previous
//
#include <hip/hip_runtime.h>
#include <float.h>
#include <math.h>

#define BATCH 4
#define NPTS 4096
#define BLK 256
#define QCH 8                      // queries/thread, chamfer
#define QR 4                       // queries/thread, repulsion
#define SEG_CH 64                  // chamfer segments (64 pts each)
#define TPTS_CH 64
#define SEG_R 64                   // repulsion segments (64 pts each)
#define TPTS_R 64
#define H2 (0.03f * 0.03f)
#define RADIUS_C 0.07f
#define EPS_C 1e-12f
#define T2 0.05f                   // rep d^2 cutoff: excluded contribs ~1e-25
#define NQ (BATCH * NPTS)          // 16384
#define NCH (2 * NQ)               // 32768 chamfer (type,b,q) rows
#define MBLK 1024                  // merge blocks (512 chamfer + 512 rep)

// d_ws (24 MB + 4 KB):
//   minseg  : float [SEG_CH][NCH]   (8 MB)   @ 0
//   top4    : float4[SEG_R][NQ]     (16 MB)  @ 8 MB
//   chamsum : float [512]                    @ 24 MB
//   repsum  : float [512]                    @ 24 MB + 2048
//
// R11 theory: R10's regression was the merge-end protocol scaling with block
// count: 1024 same-address device-scope atomics (hdr[2]) + 1024 threadfences
// + 1024 accum atomics serialize at the coherence point (per-XCD L2s not
// cross-coherent) -> tens of us. Fix: merge blocks write plain per-block sums
// (no atomics, no fences); a 1-block finalize kernel reduces 2x512 floats.
// Partial reverted to R9's exact 2048-block config (measured ~23-24us twice).

template <bool EXCL>
__device__ __forceinline__ void rep_loop(
    const float4* __restrict__ s, int base, const int (&q)[QR],
    const float (&nx)[QR], const float (&ny)[QR], const float (&nz)[QR],
    float (&m)[QR][4])
{
    #pragma unroll 2
    for (int j = 0; j < TPTS_R; ++j) {
        float4 t = s[j];
        #pragma unroll
        for (int r = 0; r < QR; ++r) {
            float hv = fmaf(nx[r], t.x, fmaf(ny[r], t.y, fmaf(nz[r], t.z, t.w)));
            if (EXCL) hv = (base + j == q[r]) ? FLT_MAX : hv;   // exclude self
            if (__any(hv < m[r][3])) {                          // per-query gate, rare
                float n0 = fminf(m[r][0], hv); float u0 = fmaxf(m[r][0], hv);
                float n1 = fminf(m[r][1], u0); float u1 = fmaxf(m[r][1], u0);
                float n2 = fminf(m[r][2], u1); float u2 = fmaxf(m[r][2], u1);
                float n3 = fminf(m[r][3], u2);
                m[r][0] = n0; m[r][1] = n1; m[r][2] = n2; m[r][3] = n3;
            }
        }
    }
}

// 2048 blocks: even bid = chamfer (qblk2 x type2 x b4 x seg64 = 1024),
//              odd  bid = repulsion (qblk4 x b4 x seg64 = 1024).
__global__ __launch_bounds__(BLK, 8) void partial_kernel(
    const float* __restrict__ pred, const float* __restrict__ gt,
    float* __restrict__ minseg, float4* __restrict__ top4)
{
    __shared__ float4 s[TPTS_R];   // 64 x (x,y,z,|t|^2) = 1 KB

    const int bid   = blockIdx.x;
    const int isrep = bid & 1;
    const int id    = bid >> 1;    // [0,1024)

    int type, b, qblk, seg;
    if (!isrep) {
        qblk = id & 1; type = (id >> 1) & 1; b = (id >> 2) & 3; seg = id >> 4;
    } else {
        qblk = id & 3; type = 2;             b = (id >> 2) & 3; seg = id >> 4;
    }
    const float* qbase = (type == 1) ? gt : pred;
    const float* tbase = (type == 0) ? gt : pred;

    // stage 64 targets: threads 0..31, 2 points each, |t|^2 on the fly
    if (threadIdx.x < 32) {
        const float2* g2 = (const float2*)(tbase + ((size_t)b * NPTS + seg * TPTS_R) * 3);
        float2 a = g2[3 * threadIdx.x + 0];
        float2 c = g2[3 * threadIdx.x + 1];
        float2 e = g2[3 * threadIdx.x + 2];
        float t20 = fmaf(a.x, a.x, fmaf(a.y, a.y, c.x * c.x));
        float t21 = fmaf(c.y, c.y, fmaf(e.x, e.x, e.y * e.y));
        s[2 * threadIdx.x + 0] = make_float4(a.x, a.y, c.x, t20);
        s[2 * threadIdx.x + 1] = make_float4(c.y, e.x, e.y, t21);
    }
    __syncthreads();

    if (!isrep) {
        const int q0 = qblk * (BLK * QCH) + threadIdx.x;      // qblk*2048 + tid
        float nx[QCH], ny[QCH], nz[QCH], q2[QCH], mn[QCH];
        #pragma unroll
        for (int k = 0; k < QCH; ++k) {
            const float* q = qbase + ((size_t)b * NPTS + q0 + k * BLK) * 3;
            float qx = q[0], qy = q[1], qz = q[2];
            q2[k] = fmaf(qx, qx, fmaf(qy, qy, qz * qz));
            nx[k] = -2.f * qx; ny[k] = -2.f * qy; nz[k] = -2.f * qz;
            mn[k] = FLT_MAX;
        }
        #pragma unroll 2
        for (int j = 0; j < TPTS_CH; j += 2) {
            float4 t0 = s[j], t1 = s[j + 1];
            #pragma unroll
            for (int k = 0; k < QCH; ++k) {
                float h0 = fmaf(nx[k], t0.x, fmaf(ny[k], t0.y, fmaf(nz[k], t0.z, t0.w)));
                float h1 = fmaf(nx[k], t1.x, fmaf(ny[k], t1.y, fmaf(nz[k], t1.z, t1.w)));
                mn[k] = fminf(fminf(mn[k], h0), h1);          // -> v_min3_f32
            }
        }
        float* row = minseg + (size_t)seg * NCH + (type * BATCH + b) * NPTS;
        #pragma unroll
        for (int k = 0; k < QCH; ++k)
            row[q0 + k * BLK] = mn[k] + q2[k];
    } else {
        const int qb = qblk * (BLK * QR) + threadIdx.x;       // qblk*1024 + tid
        int   q[QR];
        float nx[QR], ny[QR], nz[QR], q2[QR];
        float m[QR][4];
        #pragma unroll
        for (int r = 0; r < QR; ++r) {
            q[r] = qb + r * BLK;
            const float* qa = qbase + ((size_t)b * NPTS + q[r]) * 3;
            float qx = qa[0], qy = qa[1], qz = qa[2];
            q2[r] = fmaf(qx, qx, fmaf(qy, qy, qz * qz));
            nx[r] = -2.f * qx; ny[r] = -2.f * qy; nz[r] = -2.f * qz;
            // h-space cutoff init: h < T2 - q2  <=>  d2 < T2
            float a = T2 - q2[r];
            m[r][0] = a; m[r][1] = a; m[r][2] = a; m[r][3] = a;
        }
        const int base = seg * TPTS_R;
        // queries [qblk*1024, +1024) overlap targets [seg*64, +64) iff seg>>4==qblk
        if ((seg >> 4) == qblk)
            rep_loop<true >(s, base, q, nx, ny, nz, m);
        else
            rep_loop<false>(s, base, q, nx, ny, nz, m);

        float4* dst = top4 + (size_t)seg * NQ + b * NPTS;
        #pragma unroll
        for (int r = 0; r < QR; ++r)
            dst[q[r]] = make_float4(m[r][0] + q2[r], m[r][1] + q2[r],
                                    m[r][2] + q2[r], m[r][3] + q2[r]);
    }
}

// 1024 blocks: even = chamfer merge (512 x 64 queries, 4 grp x 16 segs),
// odd = rep merge (512 x 32 queries, 8 grp x 8 segs). Seg-split across
// thread groups + LDS tree -> 1 latency round. NO atomics/fences: each
// block writes one float to chamsum[c]/repsum[c].
__global__ __launch_bounds__(BLK) void merge_kernel(
    const float* __restrict__ minseg, const float4* __restrict__ top4,
    float* __restrict__ chamsum, float* __restrict__ repsum)
{
    __shared__ float4 l4[8][32];                   // rep lists; aliased for chamfer
    float* red = (float*)l4;                       // [4][64] floats for chamfer

    float contrib = 0.f;
    const int c = blockIdx.x >> 1;                 // [0,512)
    if (!(blockIdx.x & 1)) {
        // ---- chamfer: 64 queries, 4 groups x 16 segs ----
        const int q   = c * 64 + (threadIdx.x & 63);
        const int grp = threadIdx.x >> 6;          // 0..3
        float m = FLT_MAX;
        #pragma unroll                             // 16 independent loads in flight
        for (int u = 0; u < 16; ++u)
            m = fminf(m, minseg[(size_t)(grp * 16 + u) * NCH + q]);
        red[grp * 64 + (threadIdx.x & 63)] = m;
        __syncthreads();
        if (threadIdx.x < 64) {
            float mm = fminf(fminf(red[threadIdx.x],       red[64  + threadIdx.x]),
                             fminf(red[128 + threadIdx.x], red[192 + threadIdx.x]));
            contrib = fmaxf(mm, 0.f);              // clamp as in reference
        }
        if (threadIdx.x < 64) {
            #pragma unroll
            for (int off = 32; off > 0; off >>= 1)
                contrib += __shfl_down(contrib, off, 64);
            if (threadIdx.x == 0) chamsum[c] = contrib;
        }
    } else {
        // ---- repulsion: 32 queries, 8 groups x 8 segs ----
        const int q   = c * 32 + (threadIdx.x & 31);
        const int grp = threadIdx.x >> 5;          // 0..7
        float m0 = FLT_MAX, m1 = FLT_MAX, m2 = FLT_MAX, m3 = FLT_MAX;
        #pragma unroll                             // 8 float4 loads in flight
        for (int u = 0; u < 8; ++u) {
            float4 v = top4[(size_t)(grp * 8 + u) * NQ + q];
            const float vals[4] = {v.x, v.y, v.z, v.w};
            #pragma unroll
            for (int k = 0; k < 4; ++k) {
                float h = vals[k];
                if (h < m3) {                      // mostly T2 sentinel -> skip
                    float n0 = fminf(m0, h);  float u0 = fmaxf(m0, h);
                    float n1 = fminf(m1, u0); float u1 = fmaxf(m1, u0);
                    float n2 = fminf(m2, u1); float u2 = fmaxf(m2, u1);
                    float n3 = fminf(m3, u2);
                    m0 = n0; m1 = n1; m2 = n2; m3 = n3;
                }
            }
        }
        l4[grp][threadIdx.x & 31] = make_float4(m0, m1, m2, m3);
        __syncthreads();
        if (threadIdx.x < 32) {
            float p0 = FLT_MAX, p1 = FLT_MAX, p2 = FLT_MAX, p3 = FLT_MAX;
            #pragma unroll
            for (int g2 = 0; g2 < 8; ++g2) {
                float4 v = l4[g2][threadIdx.x];
                const float vals[4] = {v.x, v.y, v.z, v.w};
                #pragma unroll
                for (int k = 0; k < 4; ++k) {
                    float h = vals[k];
                    if (h < p3) {
                        float n0 = fminf(p0, h);  float u0 = fmaxf(p0, h);
                        float n1 = fminf(p1, u0); float u1 = fmaxf(p1, u0);
                        float n2 = fminf(p2, u1); float u2 = fmaxf(p2, u1);
                        float n3 = fminf(p3, u2);
                        p0 = n0; p1 = n1; p2 = n2; p3 = n3;
                    }
                }
            }
            const float ms[4] = {p0, p1, p2, p3};
            #pragma unroll
            for (int k = 0; k < 4; ++k) {
                float d2 = fmaxf(ms[k], EPS_C);
                float d  = sqrtf(d2);
                contrib += (RADIUS_C - d) * expf(-d2 * (1.f / H2));
            }
        }
        if (threadIdx.x < 64) {                    // wave 0 only; lanes 32-63 hold 0
            #pragma unroll
            for (int off = 32; off > 0; off >>= 1)
                contrib += __shfl_down(contrib, off, 64);
            if (threadIdx.x == 0) repsum[c] = contrib;
        }
    }
}

// 1 block: sum 512 chamfer + 512 rep block-partials, write outputs.
__global__ __launch_bounds__(BLK) void finalize_kernel(
    const float* __restrict__ chamsum, const float* __restrict__ repsum,
    float* __restrict__ out)
{
    __shared__ float w[8];
    float s0 = chamsum[threadIdx.x] + chamsum[threadIdx.x + 256];
    float s1 = repsum[threadIdx.x]  + repsum[threadIdx.x + 256];
    #pragma unroll
    for (int off = 32; off > 0; off >>= 1) {
        s0 += __shfl_down(s0, off, 64);
        s1 += __shfl_down(s1, off, 64);
    }
    if ((threadIdx.x & 63) == 0) {
        w[(threadIdx.x >> 6) * 2 + 0] = s0;
        w[(threadIdx.x >> 6) * 2 + 1] = s1;
    }
    __syncthreads();
    if (threadIdx.x == 0) {
        float a0 = w[0] + w[2] + w[4] + w[6];
        float a1 = w[1] + w[3] + w[5] + w[7];
        out[0] = 100.f * a0 * (1.f / NQ);
        out[1] = a1 * (1.f / (NQ * 4));
    }
}

extern "C" void kernel_launch(void* const* d_in, const int* in_sizes, int n_in,
                              void* d_out, int out_size, void* d_ws, size_t ws_size,
                              hipStream_t stream)
{
    const float* pred = (const float*)d_in[0];
    const float* gt   = (const float*)d_in[1];

    float*  minseg  = (float*)d_ws;
    float4* top4    = (float4*)((char*)d_ws + (size_t)SEG_CH * NCH * sizeof(float));
    float*  chamsum = (float*)((char*)d_ws + (size_t)SEG_CH * NCH * sizeof(float)
                                           + (size_t)SEG_R * NQ * sizeof(float4));
    float*  repsum  = chamsum + 512;

    partial_kernel<<<2048, BLK, 0, stream>>>(pred, gt, minseg, top4);
    merge_kernel<<<MBLK, BLK, 0, stream>>>(minseg, top4, chamsum, repsum);
    finalize_kernel<<<1, BLK, 0, stream>>>(chamsum, repsum, (float*)d_out);
}